// Round 9
// baseline (1125.824 us; speedup 1.0000x reference)
//
#include <hip/hip_runtime.h>

#define N_NODES 100000
#define N_EDGES 1600000
#define E_TOT   1700000   // edges + self loops
#define HEADS   8
#define CH      32
#define F       256       // HEADS*CH
#define NCHUNK  ((N_NODES + 255) / 256)   // 391

static __device__ __forceinline__ float lrelu(float v, float s) { return fmaxf(v, s * v); }

static __device__ __forceinline__ unsigned short f2bf(float f) {
    unsigned u = __float_as_uint(f);
    u += 0x7FFFu + ((u >> 16) & 1u);      // round-to-nearest-even
    return (unsigned short)(u >> 16);
}
static __device__ __forceinline__ float bf2f(unsigned short u) {
    return __uint_as_float(((unsigned)u) << 16);
}

// ======================= CSR build (once per call) =======================
__global__ __launch_bounds__(256) void k_deg_init(int* __restrict__ cnt, float* __restrict__ stats) {
    const int i = blockIdx.x * 256 + threadIdx.x;
    if (i < N_NODES) cnt[i] = 1;          // self loop
    if (blockIdx.x == 0 && threadIdx.x < 192) stats[threadIdx.x] = 0.f;
}

__global__ __launch_bounds__(256) void k_hist(const int* __restrict__ ei, int* __restrict__ cnt) {
    for (int e = blockIdx.x * 256 + threadIdx.x; e < N_EDGES; e += gridDim.x * 256)
        atomicAdd(&cnt[ei[N_EDGES + e]], 1);
}

__global__ __launch_bounds__(256) void k_scan_chunk(
    const int* __restrict__ cnt, int* __restrict__ row_start, int* __restrict__ csum)
{
    __shared__ int s[256];
    const int t = threadIdx.x;
    const int i = blockIdx.x * 256 + t;
    const int v = (i < N_NODES) ? cnt[i] : 0;
    s[t] = v;
    __syncthreads();
    for (int off = 1; off < 256; off <<= 1) {
        const int y = (t >= off) ? s[t - off] : 0;
        __syncthreads();
        s[t] += y;
        __syncthreads();
    }
    if (i < N_NODES) row_start[i] = s[t] - v;   // exclusive
    if (t == 255) csum[blockIdx.x] = s[t];
}

__global__ __launch_bounds__(512) void k_scan_top(int* __restrict__ csum) {
    __shared__ int s[512];
    const int t = threadIdx.x;
    const int v = (t < NCHUNK) ? csum[t] : 0;
    s[t] = v;
    __syncthreads();
    for (int off = 1; off < 512; off <<= 1) {
        const int y = (t >= off) ? s[t - off] : 0;
        __syncthreads();
        s[t] += y;
        __syncthreads();
    }
    if (t < NCHUNK) csum[t] = s[t] - v;         // exclusive
}

__global__ __launch_bounds__(256) void k_fill_init(
    int* __restrict__ row_start, const int* __restrict__ csum,
    int* __restrict__ cursor, int* __restrict__ csr_src)
{
    const int i = blockIdx.x * 256 + threadIdx.x;
    if (i >= N_NODES) return;
    const int rs = row_start[i] + csum[i >> 8];
    row_start[i] = rs;
    cursor[i] = rs + 1;
    csr_src[rs] = i * 64;                       // self loop first (pre-scaled: ushort4-element offset)
}

__global__ __launch_bounds__(256) void k_fill(
    const int* __restrict__ ei, int* __restrict__ cursor, int* __restrict__ csr_src)
{
    for (int e = blockIdx.x * 256 + threadIdx.x; e < N_EDGES; e += gridDim.x * 256) {
        const int pos = atomicAdd(&cursor[ei[N_EDGES + e]], 1);
        csr_src[pos] = ei[e] * 64;              // pre-scaled
    }
}
// after k_fill: cursor[i] == row_end[i]

// ====== xl = bn?(x) @ Wl (bf16), xr = bn?(x) @ Wr (bf16)  ([N,32]@[32,256]) ======
template <bool NORM>
__global__ __launch_bounds__(256) void k_gemm(
    const float* __restrict__ xin, const float* __restrict__ pstats,
    const float* __restrict__ pg, const float* __restrict__ pbe,
    const float* __restrict__ Wl, const float* __restrict__ Wr,
    unsigned short* __restrict__ xl, unsigned short* __restrict__ xr)
{
    __shared__ float xs[64 * CH];
    const int t = threadIdx.x;
    const int c = t & 31;
    float psc = 1.f, psh = 0.f;
    if (NORM) {
        const float mu  = pstats[c] * (1.f / N_NODES);
        const float var = pstats[32 + c] * (1.f / N_NODES) - mu * mu;
        psc = rsqrtf(var + 1e-5f) * pg[c];
        psh = pbe[c] - mu * psc;
    }
    float wl[CH], wr[CH];
#pragma unroll
    for (int k = 0; k < CH; ++k) {
        wl[k] = Wl[k * F + t];
        wr[k] = Wr[k * F + t];
    }
    for (int r0 = blockIdx.x * 64; r0 < N_NODES; r0 += gridDim.x * 64) {
        const int rows = min(64, N_NODES - r0);
        __syncthreads();
        for (int i = t; i < rows * CH; i += 256) {
            const float xv = xin[(size_t)r0 * CH + i];
            xs[i] = NORM ? fmaf(xv, psc, psh) : xv;
        }
        __syncthreads();
        for (int r = 0; r < rows; ++r) {
            float al = 0.f, ar = 0.f;
#pragma unroll
            for (int k = 0; k < CH; ++k) {
                const float xv = xs[r * CH + k];
                al = fmaf(xv, wl[k], al);
                ar = fmaf(xv, wr[k], ar);
            }
            xl[(size_t)(r0 + r) * F + t] = f2bf(al);
            xr[(size_t)(r0 + r) * F + t] = f2bf(ar);
        }
    }
}

// ============== fused GATv2 aggregation + post (bias/lrelu/residual/stats) ==============
// one wave per dst node; lane l: head l>>3, channels 4*(l&7)..+3
// edge loop: EXACT round-5/8 structure (unroll-2, two chains, shfl_xor reduce).
// epilogue per node: v = [lrelu](agg + bias) + bn?(xprev); y = v; stats += (v, v^2)
template <int MODE, bool NORM>   // MODE 0: leaky_relu 0.01, 1: none
__global__ __launch_bounds__(256) void k_agg(
    const int* __restrict__ row_start, const int* __restrict__ row_end,
    const int* __restrict__ csr_src, const unsigned short* __restrict__ xl,
    const unsigned short* __restrict__ xr, const float* __restrict__ att,
    const float* __restrict__ xprev, const float* __restrict__ pstats,
    const float* __restrict__ pg, const float* __restrict__ pbe,
    const float* __restrict__ bias, float* __restrict__ y,
    float* __restrict__ stats)
{
    __shared__ float sred[4][8][8];
    const int t    = threadIdx.x;
    const int lane = t & 63;
    const int wv   = t >> 6;
    const int l8   = lane & 7;
    const int wid  = (blockIdx.x * blockDim.x + t) >> 6;
    const int nw   = (gridDim.x * blockDim.x) >> 6;
    const float4 a4 = ((const float4*)att)[lane];
    const float4 b4 = ((const float4*)bias)[l8];
    float4 psc = make_float4(1.f, 1.f, 1.f, 1.f), psh = make_float4(0.f, 0.f, 0.f, 0.f);
    if (NORM) {
        const float4 m4 = ((const float4*)pstats)[l8];
        const float4 q4 = ((const float4*)(pstats + 32))[l8];
        const float4 g4 = ((const float4*)pg)[l8];
        const float4 e4 = ((const float4*)pbe)[l8];
        float mu;
        mu = m4.x * (1.f / N_NODES); psc.x = rsqrtf(q4.x * (1.f / N_NODES) - mu * mu + 1e-5f) * g4.x; psh.x = e4.x - mu * psc.x;
        mu = m4.y * (1.f / N_NODES); psc.y = rsqrtf(q4.y * (1.f / N_NODES) - mu * mu + 1e-5f) * g4.y; psh.y = e4.y - mu * psc.y;
        mu = m4.z * (1.f / N_NODES); psc.z = rsqrtf(q4.z * (1.f / N_NODES) - mu * mu + 1e-5f) * g4.z; psh.z = e4.z - mu * psc.z;
        mu = m4.w * (1.f / N_NODES); psc.w = rsqrtf(q4.w * (1.f / N_NODES) - mu * mu + 1e-5f) * g4.w; psh.w = e4.w - mu * psc.w;
    }
    float ls0 = 0.f, ls1 = 0.f, ls2 = 0.f, ls3 = 0.f;
    float lq0 = 0.f, lq1 = 0.f, lq2 = 0.f, lq3 = 0.f;
    const ushort4* __restrict__ xl4 = (const ushort4*)xl;
    for (int n = wid; n < N_NODES; n += nw) {
        const ushort4 vru = ((const ushort4*)(xr + (size_t)n * F))[lane];
        const float rx = bf2f(vru.x), ry = bf2f(vru.y), rz = bf2f(vru.z), rw = bf2f(vru.w);
        float c0a = 0.f, c1a = 0.f, c2a = 0.f, c3a = 0.f, dena = 0.f;
        float c0b = 0.f, c1b = 0.f, c2b = 0.f, c3b = 0.f, denb = 0.f;
        const int e0 = row_start[n], e1 = row_end[n];
        int e = e0;
        for (; e + 1 < e1; e += 2) {
            const unsigned ia = (unsigned)csr_src[e]     + (unsigned)lane;
            const unsigned ib = (unsigned)csr_src[e + 1] + (unsigned)lane;
            const ushort4 va = xl4[ia];           // both loads issued before any use:
            const ushort4 vb = xl4[ib];           // two gathers in flight
            const float ax = bf2f(va.x), ay = bf2f(va.y), az = bf2f(va.z), aw = bf2f(va.w);
            const float bx = bf2f(vb.x), by = bf2f(vb.y), bz = bf2f(vb.z), bw = bf2f(vb.w);
            float sA = lrelu(ax + rx, 0.2f) * a4.x
                     + lrelu(ay + ry, 0.2f) * a4.y
                     + lrelu(az + rz, 0.2f) * a4.z
                     + lrelu(aw + rw, 0.2f) * a4.w;
            float sB = lrelu(bx + rx, 0.2f) * a4.x
                     + lrelu(by + ry, 0.2f) * a4.y
                     + lrelu(bz + rz, 0.2f) * a4.z
                     + lrelu(bw + rw, 0.2f) * a4.w;
            sA += __shfl_xor(sA, 1);  sB += __shfl_xor(sB, 1);
            sA += __shfl_xor(sA, 2);  sB += __shfl_xor(sB, 2);
            sA += __shfl_xor(sA, 4);  sB += __shfl_xor(sB, 4);
            const float pA = __expf(sA);
            const float pB = __expf(sB);
            dena += pA;                denb += pB;
            c0a = fmaf(pA, ax, c0a);   c0b = fmaf(pB, bx, c0b);
            c1a = fmaf(pA, ay, c1a);   c1b = fmaf(pB, by, c1b);
            c2a = fmaf(pA, az, c2a);   c2b = fmaf(pB, bz, c2b);
            c3a = fmaf(pA, aw, c3a);   c3b = fmaf(pB, bw, c3b);
        }
        if (e < e1) {                              // remainder edge
            const unsigned ia = (unsigned)csr_src[e] + (unsigned)lane;
            const ushort4 va = xl4[ia];
            const float ax = bf2f(va.x), ay = bf2f(va.y), az = bf2f(va.z), aw = bf2f(va.w);
            float sA = lrelu(ax + rx, 0.2f) * a4.x
                     + lrelu(ay + ry, 0.2f) * a4.y
                     + lrelu(az + rz, 0.2f) * a4.z
                     + lrelu(aw + rw, 0.2f) * a4.w;
            sA += __shfl_xor(sA, 1);
            sA += __shfl_xor(sA, 2);
            sA += __shfl_xor(sA, 4);
            const float pA = __expf(sA);
            dena += pA;
            c0a = fmaf(pA, ax, c0a);
            c1a = fmaf(pA, ay, c1a);
            c2a = fmaf(pA, az, c2a);
            c3a = fmaf(pA, aw, c3a);
        }
        float c0 = c0a + c0b, c1 = c1a + c1b, c2 = c2a + c2b, c3 = c3a + c3b;
        const float inv = 0.125f / (dena + denb);  // alpha-normalize + head-mean
        c0 *= inv; c1 *= inv; c2 *= inv; c3 *= inv;
#pragma unroll
        for (int off = 8; off <= 32; off <<= 1) {  // sum the 8 heads (butterfly: all lanes valid)
            c0 += __shfl_xor(c0, off);
            c1 += __shfl_xor(c1, off);
            c2 += __shfl_xor(c2, off);
            c3 += __shfl_xor(c3, off);
        }
        // ---- fused post (all lanes hold channels 4*l8..+3; 8-fold duplicates) ----
        const float4 xp = ((const float4*)(xprev + (size_t)n * CH))[l8];
        float v0 = c0 + b4.x, v1 = c1 + b4.y, v2 = c2 + b4.z, v3 = c3 + b4.w;
        if (MODE == 0) {
            v0 = lrelu(v0, 0.01f); v1 = lrelu(v1, 0.01f);
            v2 = lrelu(v2, 0.01f); v3 = lrelu(v3, 0.01f);
        }
        v0 += NORM ? fmaf(xp.x, psc.x, psh.x) : xp.x;
        v1 += NORM ? fmaf(xp.y, psc.y, psh.y) : xp.y;
        v2 += NORM ? fmaf(xp.z, psc.z, psh.z) : xp.z;
        v3 += NORM ? fmaf(xp.w, psc.w, psh.w) : xp.w;
        if (lane < 8)
            ((float4*)(y + (size_t)n * CH))[l8] = make_float4(v0, v1, v2, v3);
        ls0 += v0; lq0 = fmaf(v0, v0, lq0);
        ls1 += v1; lq1 = fmaf(v1, v1, lq1);
        ls2 += v2; lq2 = fmaf(v2, v2, lq2);
        ls3 += v3; lq3 = fmaf(v3, v3, lq3);
    }
    // ---- block stats reduce (lane<8 copies are exact per-wave partials) ----
    if (lane < 8) {
        sred[wv][l8][0] = ls0; sred[wv][l8][1] = ls1;
        sred[wv][l8][2] = ls2; sred[wv][l8][3] = ls3;
        sred[wv][l8][4] = lq0; sred[wv][l8][5] = lq1;
        sred[wv][l8][6] = lq2; sred[wv][l8][7] = lq3;
    }
    __syncthreads();
    if (t < 32) {
        float s = 0.f, q = 0.f;
#pragma unroll
        for (int w = 0; w < 4; ++w) {
            s += sred[w][t >> 2][t & 3];
            q += sred[w][t >> 2][4 + (t & 3)];
        }
        atomicAdd(&stats[t], s);
        atomicAdd(&stats[32 + t], q);
    }
}

// ============== final batchnorm normalize → d_out ==============
__global__ __launch_bounds__(256) void k_bn(
    const float* __restrict__ y, const float* __restrict__ stats,
    const float* __restrict__ g, const float* __restrict__ be,
    float* __restrict__ xo)
{
    const int t = threadIdx.x;
    const int c = t & 31;
    const float mu  = stats[c] * (1.f / N_NODES);
    const float var = stats[32 + c] * (1.f / N_NODES) - mu * mu;
    const float sc  = rsqrtf(var + 1e-5f) * g[c];
    const float sh  = be[c] - mu * sc;
    for (int i = blockIdx.x * 256 + t; i < N_NODES * CH; i += gridDim.x * 256)
        xo[i] = fmaf(y[i], sc, sh);
}

extern "C" void kernel_launch(void* const* d_in, const int* in_sizes, int n_in,
                              void* d_out, int out_size, void* d_ws, size_t ws_size,
                              hipStream_t stream)
{
    const float* x0 = (const float*)d_in[0];
    const int*   ei = (const int*)d_in[1];

    char* ws = (char*)d_ws;
    unsigned short* xl    = (unsigned short*)ws;                          // N*256 bf16  51.2 MB
    unsigned short* xr    = xl + (size_t)N_NODES * F;                     // N*256 bf16  51.2 MB
    float*          accA  = (float*)(xr + (size_t)N_NODES * F);           // N*32  f32   12.8 MB
    float*          accB  = accA + (size_t)N_NODES * CH;                  // N*32  f32   12.8 MB
    float*          stats = accB + (size_t)N_NODES * CH;                  // 3*64
    int*            cnt   = (int*)(stats + 192);                          // N (cursor/row_end)
    int*            rowst = cnt + N_NODES;                                // N
    int*            csum  = rowst + N_NODES;                              // NCHUNK
    int*            csr   = csum + NCHUNK;                                // E_TOT  6.8 MB
    const size_t needed = (size_t)((char*)(csr + E_TOT) - ws);            // ~136 MB
    if (ws_size < needed) return;

    const float *Wl[3], *Wr[3], *att[3], *bb[3], *gg[3], *be[3];
    for (int L = 0; L < 3; ++L) {
        Wl[L]  = (const float*)d_in[3 + 6 * L + 0];
        Wr[L]  = (const float*)d_in[3 + 6 * L + 1];
        att[L] = (const float*)d_in[3 + 6 * L + 2];
        bb[L]  = (const float*)d_in[3 + 6 * L + 3];
        gg[L]  = (const float*)d_in[3 + 6 * L + 4];
        be[L]  = (const float*)d_in[3 + 6 * L + 5];
    }
    float* st0 = stats, *st1 = stats + 64, *st2 = stats + 128;

    // ---- CSR build (identical for all 3 layers) ----
    k_deg_init <<<NCHUNK, 256, 0, stream>>>(cnt, stats);
    k_hist     <<<1024,   256, 0, stream>>>(ei, cnt);
    k_scan_chunk<<<NCHUNK, 256, 0, stream>>>(cnt, rowst, csum);
    k_scan_top <<<1,      512, 0, stream>>>(csum);
    k_fill_init<<<NCHUNK, 256, 0, stream>>>(rowst, csum, cnt, csr);
    k_fill     <<<1024,   256, 0, stream>>>(ei, cnt, csr);

    // ---- layer 0: input x0 (raw) ----
    k_gemm<false><<<1563, 256, 0, stream>>>(x0, nullptr, nullptr, nullptr, Wl[0], Wr[0], xl, xr);
    k_agg<0, false><<<2048, 256, 0, stream>>>(rowst, cnt, csr, xl, xr, att[0],
                                              x0, nullptr, nullptr, nullptr, bb[0], accA, st0);

    // ---- layer 1: input bn(accA; st0, g0, be0) ----
    k_gemm<true><<<1563, 256, 0, stream>>>(accA, st0, gg[0], be[0], Wl[1], Wr[1], xl, xr);
    k_agg<0, true><<<2048, 256, 0, stream>>>(rowst, cnt, csr, xl, xr, att[1],
                                             accA, st0, gg[0], be[0], bb[1], accB, st1);

    // ---- layer 2: input bn(accB; st1, g1, be1) ----
    k_gemm<true><<<1563, 256, 0, stream>>>(accB, st1, gg[1], be[1], Wl[2], Wr[2], xl, xr);
    k_agg<1, true><<<2048, 256, 0, stream>>>(rowst, cnt, csr, xl, xr, att[2],
                                             accB, st1, gg[1], be[1], bb[2], accA, st2);

    // ---- final BN -> d_out ----
    k_bn<<<2048, 256, 0, stream>>>(accA, st2, gg[2], be[2], (float*)d_out);

    (void)in_sizes; (void)n_in; (void)out_size;
}

// Round 10
// 944.815 us; speedup vs baseline: 1.1916x; 1.1916x over previous
//
#include <hip/hip_runtime.h>

#define N_NODES 100000
#define N_EDGES 1600000
#define E_TOT   1700000   // edges + self loops
#define HEADS   8
#define CH      32
#define F       256       // HEADS*CH
#define NCHUNK  ((N_NODES + 255) / 256)   // 391

static __device__ __forceinline__ float lrelu(float v, float s) { return fmaxf(v, s * v); }

static __device__ __forceinline__ unsigned short f2bf(float f) {
    unsigned u = __float_as_uint(f);
    u += 0x7FFFu + ((u >> 16) & 1u);      // round-to-nearest-even
    return (unsigned short)(u >> 16);
}
static __device__ __forceinline__ float bf2f(unsigned short u) {
    return __uint_as_float(((unsigned)u) << 16);
}

// 8-lane sum via DPP (VALU-only, no DS pipe; ~6 cheap ops vs 3x ~60cyc ds_swizzle).
// xor1 + xor2 within quads -> every lane holds its quad sum; row_half_mirror
// (l -> 7-l within each 8-lane half-row) supplies the other quad's sum.
// Validated correct in round 6 (absmax identical to shfl_xor path).
static __device__ __forceinline__ float dpp_sum8(float s) {
    s += __uint_as_float(__builtin_amdgcn_mov_dpp(__float_as_uint(s), 0xB1, 0xF, 0xF, true));  // quad_perm [1,0,3,2]
    s += __uint_as_float(__builtin_amdgcn_mov_dpp(__float_as_uint(s), 0x4E, 0xF, 0xF, true));  // quad_perm [2,3,0,1]
    s += __uint_as_float(__builtin_amdgcn_mov_dpp(__float_as_uint(s), 0x141, 0xF, 0xF, true)); // row_half_mirror
    return s;
}

// ======================= CSR build (once per call) =======================
__global__ __launch_bounds__(256) void k_deg_init(int* __restrict__ cnt, float* __restrict__ stats) {
    const int i = blockIdx.x * 256 + threadIdx.x;
    if (i < N_NODES) cnt[i] = 1;          // self loop
    if (blockIdx.x == 0 && threadIdx.x < 192) stats[threadIdx.x] = 0.f;
}

__global__ __launch_bounds__(256) void k_hist(const int* __restrict__ ei, int* __restrict__ cnt) {
    for (int e = blockIdx.x * 256 + threadIdx.x; e < N_EDGES; e += gridDim.x * 256)
        atomicAdd(&cnt[ei[N_EDGES + e]], 1);
}

__global__ __launch_bounds__(256) void k_scan_chunk(
    const int* __restrict__ cnt, int* __restrict__ row_start, int* __restrict__ csum)
{
    __shared__ int s[256];
    const int t = threadIdx.x;
    const int i = blockIdx.x * 256 + t;
    const int v = (i < N_NODES) ? cnt[i] : 0;
    s[t] = v;
    __syncthreads();
    for (int off = 1; off < 256; off <<= 1) {
        const int y = (t >= off) ? s[t - off] : 0;
        __syncthreads();
        s[t] += y;
        __syncthreads();
    }
    if (i < N_NODES) row_start[i] = s[t] - v;   // exclusive
    if (t == 255) csum[blockIdx.x] = s[t];
}

__global__ __launch_bounds__(512) void k_scan_top(int* __restrict__ csum) {
    __shared__ int s[512];
    const int t = threadIdx.x;
    const int v = (t < NCHUNK) ? csum[t] : 0;
    s[t] = v;
    __syncthreads();
    for (int off = 1; off < 512; off <<= 1) {
        const int y = (t >= off) ? s[t - off] : 0;
        __syncthreads();
        s[t] += y;
        __syncthreads();
    }
    if (t < NCHUNK) csum[t] = s[t] - v;         // exclusive
}

__global__ __launch_bounds__(256) void k_fill_init(
    int* __restrict__ row_start, const int* __restrict__ csum,
    int* __restrict__ cursor, int* __restrict__ csr_src)
{
    const int i = blockIdx.x * 256 + threadIdx.x;
    if (i >= N_NODES) return;
    const int rs = row_start[i] + csum[i >> 8];
    row_start[i] = rs;
    cursor[i] = rs + 1;
    csr_src[rs] = i * 64;                       // self loop first (pre-scaled: ushort4-element offset)
}

__global__ __launch_bounds__(256) void k_fill(
    const int* __restrict__ ei, int* __restrict__ cursor, int* __restrict__ csr_src)
{
    for (int e = blockIdx.x * 256 + threadIdx.x; e < N_EDGES; e += gridDim.x * 256) {
        const int pos = atomicAdd(&cursor[ei[N_EDGES + e]], 1);
        csr_src[pos] = ei[e] * 64;              // pre-scaled
    }
}
// after k_fill: cursor[i] == row_end[i]

// ====== xl = bn?(x) @ Wl (bf16), xr = bn?(x) @ Wr (bf16)  ([N,32]@[32,256]) ======
template <bool NORM>
__global__ __launch_bounds__(256) void k_gemm(
    const float* __restrict__ xin, const float* __restrict__ pstats,
    const float* __restrict__ pg, const float* __restrict__ pbe,
    const float* __restrict__ Wl, const float* __restrict__ Wr,
    unsigned short* __restrict__ xl, unsigned short* __restrict__ xr)
{
    __shared__ float xs[64 * CH];
    const int t = threadIdx.x;
    const int c = t & 31;
    float psc = 1.f, psh = 0.f;
    if (NORM) {
        const float mu  = pstats[c] * (1.f / N_NODES);
        const float var = pstats[32 + c] * (1.f / N_NODES) - mu * mu;
        psc = rsqrtf(var + 1e-5f) * pg[c];
        psh = pbe[c] - mu * psc;
    }
    float wl[CH], wr[CH];
#pragma unroll
    for (int k = 0; k < CH; ++k) {
        wl[k] = Wl[k * F + t];
        wr[k] = Wr[k * F + t];
    }
    for (int r0 = blockIdx.x * 64; r0 < N_NODES; r0 += gridDim.x * 64) {
        const int rows = min(64, N_NODES - r0);
        __syncthreads();
        for (int i = t; i < rows * CH; i += 256) {
            const float xv = xin[(size_t)r0 * CH + i];
            xs[i] = NORM ? fmaf(xv, psc, psh) : xv;
        }
        __syncthreads();
        for (int r = 0; r < rows; ++r) {
            float al = 0.f, ar = 0.f;
#pragma unroll
            for (int k = 0; k < CH; ++k) {
                const float xv = xs[r * CH + k];
                al = fmaf(xv, wl[k], al);
                ar = fmaf(xv, wr[k], ar);
            }
            xl[(size_t)(r0 + r) * F + t] = f2bf(al);
            xr[(size_t)(r0 + r) * F + t] = f2bf(ar);
        }
    }
}

// ============== single-pass GATv2 aggregation: one wave per dst node ==============
// lane l: head l>>3, channels 4*(l&7)..+3
// Round-8 structure (unroll-2, two chains); ONLY change: dpp_sum8 replaces 3x shfl_xor.
__global__ __launch_bounds__(256) void k_agg(
    const int* __restrict__ row_start, const int* __restrict__ row_end,
    const int* __restrict__ csr_src, const unsigned short* __restrict__ xl,
    const unsigned short* __restrict__ xr, const float* __restrict__ att,
    float* __restrict__ accum)
{
    const int lane = threadIdx.x & 63;
    const int wid  = (blockIdx.x * blockDim.x + threadIdx.x) >> 6;
    const int nw   = (gridDim.x * blockDim.x) >> 6;
    const float4 a4 = ((const float4*)att)[lane];
    const ushort4* __restrict__ xl4 = (const ushort4*)xl;
    for (int n = wid; n < N_NODES; n += nw) {
        const ushort4 vru = ((const ushort4*)(xr + (size_t)n * F))[lane];
        const float rx = bf2f(vru.x), ry = bf2f(vru.y), rz = bf2f(vru.z), rw = bf2f(vru.w);
        float c0a = 0.f, c1a = 0.f, c2a = 0.f, c3a = 0.f, dena = 0.f;
        float c0b = 0.f, c1b = 0.f, c2b = 0.f, c3b = 0.f, denb = 0.f;
        const int e0 = row_start[n], e1 = row_end[n];
        int e = e0;
        for (; e + 1 < e1; e += 2) {
            const unsigned ia = (unsigned)csr_src[e]     + (unsigned)lane;
            const unsigned ib = (unsigned)csr_src[e + 1] + (unsigned)lane;
            const ushort4 va = xl4[ia];           // both loads issued before any use:
            const ushort4 vb = xl4[ib];           // two gathers in flight
            const float ax = bf2f(va.x), ay = bf2f(va.y), az = bf2f(va.z), aw = bf2f(va.w);
            const float bx = bf2f(vb.x), by = bf2f(vb.y), bz = bf2f(vb.z), bw = bf2f(vb.w);
            float sA = lrelu(ax + rx, 0.2f) * a4.x
                     + lrelu(ay + ry, 0.2f) * a4.y
                     + lrelu(az + rz, 0.2f) * a4.z
                     + lrelu(aw + rw, 0.2f) * a4.w;
            float sB = lrelu(bx + rx, 0.2f) * a4.x
                     + lrelu(by + ry, 0.2f) * a4.y
                     + lrelu(bz + rz, 0.2f) * a4.z
                     + lrelu(bw + rw, 0.2f) * a4.w;
            sA = dpp_sum8(sA);
            sB = dpp_sum8(sB);
            const float pA = __expf(sA);
            const float pB = __expf(sB);
            dena += pA;                denb += pB;
            c0a = fmaf(pA, ax, c0a);   c0b = fmaf(pB, bx, c0b);
            c1a = fmaf(pA, ay, c1a);   c1b = fmaf(pB, by, c1b);
            c2a = fmaf(pA, az, c2a);   c2b = fmaf(pB, bz, c2b);
            c3a = fmaf(pA, aw, c3a);   c3b = fmaf(pB, bw, c3b);
        }
        if (e < e1) {                              // remainder edge
            const unsigned ia = (unsigned)csr_src[e] + (unsigned)lane;
            const ushort4 va = xl4[ia];
            const float ax = bf2f(va.x), ay = bf2f(va.y), az = bf2f(va.z), aw = bf2f(va.w);
            float sA = lrelu(ax + rx, 0.2f) * a4.x
                     + lrelu(ay + ry, 0.2f) * a4.y
                     + lrelu(az + rz, 0.2f) * a4.z
                     + lrelu(aw + rw, 0.2f) * a4.w;
            sA = dpp_sum8(sA);
            const float pA = __expf(sA);
            dena += pA;
            c0a = fmaf(pA, ax, c0a);
            c1a = fmaf(pA, ay, c1a);
            c2a = fmaf(pA, az, c2a);
            c3a = fmaf(pA, aw, c3a);
        }
        float c0 = c0a + c0b, c1 = c1a + c1b, c2 = c2a + c2b, c3 = c3a + c3b;
        const float inv = 0.125f / (dena + denb);  // alpha-normalize + head-mean
        c0 *= inv; c1 *= inv; c2 *= inv; c3 *= inv;
#pragma unroll
        for (int off = 8; off <= 32; off <<= 1) {  // sum the 8 heads (per-node, stays on shfl)
            c0 += __shfl_xor(c0, off);
            c1 += __shfl_xor(c1, off);
            c2 += __shfl_xor(c2, off);
            c3 += __shfl_xor(c3, off);
        }
        if (lane < 8)
            ((float4*)(accum + (size_t)n * CH))[lane] = make_float4(c0, c1, c2, c3);
    }
}

// ====== post: y = [lrelu](acc+bias) + residual(bn?(xprev)); batch stats ======
template <int MODE, bool NORM>   // MODE 0: leaky_relu 0.01 + residual, 1: residual only
__global__ __launch_bounds__(256) void k_post(
    float* __restrict__ y, const float* __restrict__ xprev,
    const float* __restrict__ pstats, const float* __restrict__ pg,
    const float* __restrict__ pbe, const float* __restrict__ bias,
    float* __restrict__ stats)
{
    __shared__ float s1[256], s2[256];
    const int t = threadIdx.x;
    const int c = t & 31;
    const float b = bias[c];
    float psc = 1.f, psh = 0.f;
    if (NORM) {
        const float mu  = pstats[c] * (1.f / N_NODES);
        const float var = pstats[32 + c] * (1.f / N_NODES) - mu * mu;
        psc = rsqrtf(var + 1e-5f) * pg[c];
        psh = pbe[c] - mu * psc;
    }
    float ls = 0.f, lq = 0.f;
    for (int i = blockIdx.x * 256 + t; i < N_NODES * CH; i += gridDim.x * 256) {
        float v = y[i] + b;
        if (MODE == 0) v = lrelu(v, 0.01f);
        const float xr_ = xprev[i];
        v += NORM ? fmaf(xr_, psc, psh) : xr_;
        y[i] = v;
        ls += v;
        lq = fmaf(v, v, lq);
    }
    s1[t] = ls; s2[t] = lq;
    __syncthreads();
    if (t < 32) {
        for (int j = 1; j < 8; ++j) { ls += s1[t + 32 * j]; lq += s2[t + 32 * j]; }
        atomicAdd(&stats[c], ls);
        atomicAdd(&stats[32 + c], lq);
    }
}

// ============== final batchnorm normalize → d_out ==============
__global__ __launch_bounds__(256) void k_bn(
    const float* __restrict__ y, const float* __restrict__ stats,
    const float* __restrict__ g, const float* __restrict__ be,
    float* __restrict__ xo)
{
    const int t = threadIdx.x;
    const int c = t & 31;
    const float mu  = stats[c] * (1.f / N_NODES);
    const float var = stats[32 + c] * (1.f / N_NODES) - mu * mu;
    const float sc  = rsqrtf(var + 1e-5f) * g[c];
    const float sh  = be[c] - mu * sc;
    for (int i = blockIdx.x * 256 + t; i < N_NODES * CH; i += gridDim.x * 256)
        xo[i] = fmaf(y[i], sc, sh);
}

extern "C" void kernel_launch(void* const* d_in, const int* in_sizes, int n_in,
                              void* d_out, int out_size, void* d_ws, size_t ws_size,
                              hipStream_t stream)
{
    const float* x0 = (const float*)d_in[0];
    const int*   ei = (const int*)d_in[1];

    char* ws = (char*)d_ws;
    unsigned short* xl    = (unsigned short*)ws;                          // N*256 bf16  51.2 MB
    unsigned short* xr    = xl + (size_t)N_NODES * F;                     // N*256 bf16  51.2 MB
    float*          accA  = (float*)(xr + (size_t)N_NODES * F);           // N*32  f32   12.8 MB
    float*          accB  = accA + (size_t)N_NODES * CH;                  // N*32  f32   12.8 MB
    float*          stats = accB + (size_t)N_NODES * CH;                  // 3*64
    int*            cnt   = (int*)(stats + 192);                          // N (cursor/row_end)
    int*            rowst = cnt + N_NODES;                                // N
    int*            csum  = rowst + N_NODES;                              // NCHUNK
    int*            csr   = csum + NCHUNK;                                // E_TOT  6.8 MB
    const size_t needed = (size_t)((char*)(csr + E_TOT) - ws);            // ~136 MB
    if (ws_size < needed) return;

    const float *Wl[3], *Wr[3], *att[3], *bb[3], *gg[3], *be[3];
    for (int L = 0; L < 3; ++L) {
        Wl[L]  = (const float*)d_in[3 + 6 * L + 0];
        Wr[L]  = (const float*)d_in[3 + 6 * L + 1];
        att[L] = (const float*)d_in[3 + 6 * L + 2];
        bb[L]  = (const float*)d_in[3 + 6 * L + 3];
        gg[L]  = (const float*)d_in[3 + 6 * L + 4];
        be[L]  = (const float*)d_in[3 + 6 * L + 5];
    }
    float* st0 = stats, *st1 = stats + 64, *st2 = stats + 128;

    // ---- CSR build (identical for all 3 layers) ----
    k_deg_init <<<NCHUNK, 256, 0, stream>>>(cnt, stats);
    k_hist     <<<1024,   256, 0, stream>>>(ei, cnt);
    k_scan_chunk<<<NCHUNK, 256, 0, stream>>>(cnt, rowst, csum);
    k_scan_top <<<1,      512, 0, stream>>>(csum);
    k_fill_init<<<NCHUNK, 256, 0, stream>>>(rowst, csum, cnt, csr);
    k_fill     <<<1024,   256, 0, stream>>>(ei, cnt, csr);

    // ---- layer 0: input x0 (raw) ----
    k_gemm<false><<<1563, 256, 0, stream>>>(x0, nullptr, nullptr, nullptr, Wl[0], Wr[0], xl, xr);
    k_agg        <<<2048, 256, 0, stream>>>(rowst, cnt, csr, xl, xr, att[0], accA);
    k_post<0, false><<<1024, 256, 0, stream>>>(accA, x0, nullptr, nullptr, nullptr, bb[0], st0);

    // ---- layer 1: input bn(accA; st0, g0, be0) ----
    k_gemm<true><<<1563, 256, 0, stream>>>(accA, st0, gg[0], be[0], Wl[1], Wr[1], xl, xr);
    k_agg       <<<2048, 256, 0, stream>>>(rowst, cnt, csr, xl, xr, att[1], accB);
    k_post<0, true><<<1024, 256, 0, stream>>>(accB, accA, st0, gg[0], be[0], bb[1], st1);

    // ---- layer 2: input bn(accB; st1, g1, be1) ----
    k_gemm<true><<<1563, 256, 0, stream>>>(accB, st1, gg[1], be[1], Wl[2], Wr[2], xl, xr);
    k_agg       <<<2048, 256, 0, stream>>>(rowst, cnt, csr, xl, xr, att[2], accA);
    k_post<1, true><<<1024, 256, 0, stream>>>(accA, accB, st1, gg[1], be[1], bb[2], st2);

    // ---- final BN -> d_out ----
    k_bn<<<2048, 256, 0, stream>>>(accA, st2, gg[2], be[2], (float*)d_out);

    (void)in_sizes; (void)n_in; (void)out_size;
}

// Round 11
// 912.745 us; speedup vs baseline: 1.2334x; 1.0351x over previous
//
#include <hip/hip_runtime.h>

#define N_NODES 100000
#define N_EDGES 1600000
#define E_TOT   1700000   // edges + self loops
#define HEADS   8
#define CH      32
#define F       256       // HEADS*CH
#define NCHUNK  ((N_NODES + 255) / 256)   // 391

static __device__ __forceinline__ float lrelu(float v, float s) { return fmaxf(v, s * v); }

static __device__ __forceinline__ unsigned short f2bf(float f) {
    unsigned u = __float_as_uint(f);
    u += 0x7FFFu + ((u >> 16) & 1u);      // round-to-nearest-even
    return (unsigned short)(u >> 16);
}
static __device__ __forceinline__ float bf2f(unsigned short u) {
    return __uint_as_float(((unsigned)u) << 16);
}

// 8-lane sum via DPP (VALU-only; validated r6/r10, +2% over ds_swizzle path)
static __device__ __forceinline__ float dpp_sum8(float s) {
    s += __uint_as_float(__builtin_amdgcn_mov_dpp(__float_as_uint(s), 0xB1, 0xF, 0xF, true));  // quad_perm [1,0,3,2]
    s += __uint_as_float(__builtin_amdgcn_mov_dpp(__float_as_uint(s), 0x4E, 0xF, 0xF, true));  // quad_perm [2,3,0,1]
    s += __uint_as_float(__builtin_amdgcn_mov_dpp(__float_as_uint(s), 0x141, 0xF, 0xF, true)); // row_half_mirror
    return s;
}

// ======================= CSR build (once per call) =======================
__global__ __launch_bounds__(256) void k_deg_init(int* __restrict__ cnt, float* __restrict__ stats) {
    const int i = blockIdx.x * 256 + threadIdx.x;
    if (i < N_NODES) cnt[i] = 1;          // self loop
    if (blockIdx.x == 0 && threadIdx.x < 192) stats[threadIdx.x] = 0.f;
}

__global__ __launch_bounds__(256) void k_hist(const int* __restrict__ ei, int* __restrict__ cnt) {
    for (int e = blockIdx.x * 256 + threadIdx.x; e < N_EDGES; e += gridDim.x * 256)
        atomicAdd(&cnt[ei[N_EDGES + e]], 1);
}

__global__ __launch_bounds__(256) void k_scan_chunk(
    const int* __restrict__ cnt, int* __restrict__ row_start, int* __restrict__ csum)
{
    __shared__ int s[256];
    const int t = threadIdx.x;
    const int i = blockIdx.x * 256 + t;
    const int v = (i < N_NODES) ? cnt[i] : 0;
    s[t] = v;
    __syncthreads();
    for (int off = 1; off < 256; off <<= 1) {
        const int y = (t >= off) ? s[t - off] : 0;
        __syncthreads();
        s[t] += y;
        __syncthreads();
    }
    if (i < N_NODES) row_start[i] = s[t] - v;   // exclusive
    if (t == 255) csum[blockIdx.x] = s[t];
}

__global__ __launch_bounds__(512) void k_scan_top(int* __restrict__ csum) {
    __shared__ int s[512];
    const int t = threadIdx.x;
    const int v = (t < NCHUNK) ? csum[t] : 0;
    s[t] = v;
    __syncthreads();
    for (int off = 1; off < 512; off <<= 1) {
        const int y = (t >= off) ? s[t - off] : 0;
        __syncthreads();
        s[t] += y;
        __syncthreads();
    }
    if (t < NCHUNK) csum[t] = s[t] - v;         // exclusive
}

__global__ __launch_bounds__(256) void k_fill_init(
    int* __restrict__ row_start, const int* __restrict__ csum,
    int* __restrict__ cursor, int* __restrict__ csr_src)
{
    const int i = blockIdx.x * 256 + threadIdx.x;
    if (i >= N_NODES) return;
    const int rs = row_start[i] + csum[i >> 8];
    row_start[i] = rs;
    cursor[i] = rs + 1;
    csr_src[rs] = i * 64;                       // self loop first (pre-scaled: ushort4-element offset)
}

__global__ __launch_bounds__(256) void k_fill(
    const int* __restrict__ ei, int* __restrict__ cursor, int* __restrict__ csr_src)
{
    for (int e = blockIdx.x * 256 + threadIdx.x; e < N_EDGES; e += gridDim.x * 256) {
        const int pos = atomicAdd(&cursor[ei[N_EDGES + e]], 1);
        csr_src[pos] = ei[e] * 64;              // pre-scaled
    }
}
// after k_fill: cursor[i] == row_end[i]

// ====== xl = bn?(x) @ Wl (bf16), xr = bn?(x) @ Wr (bf16)  ([N,32]@[32,256]) ======
// float4 LDS reads: 1 ds_read_b128 per 8 FMA (was 1 ds_read_b32 per 2 FMA)
template <bool NORM>
__global__ __launch_bounds__(256) void k_gemm(
    const float* __restrict__ xin, const float* __restrict__ pstats,
    const float* __restrict__ pg, const float* __restrict__ pbe,
    const float* __restrict__ Wl, const float* __restrict__ Wr,
    unsigned short* __restrict__ xl, unsigned short* __restrict__ xr)
{
    __shared__ float xs[64 * CH];
    const int t = threadIdx.x;
    const int c = t & 31;
    float psc = 1.f, psh = 0.f;
    if (NORM) {
        const float mu  = pstats[c] * (1.f / N_NODES);
        const float var = pstats[32 + c] * (1.f / N_NODES) - mu * mu;
        psc = rsqrtf(var + 1e-5f) * pg[c];
        psh = pbe[c] - mu * psc;
    }
    float wl[CH], wr[CH];
#pragma unroll
    for (int k = 0; k < CH; ++k) {
        wl[k] = Wl[k * F + t];
        wr[k] = Wr[k * F + t];
    }
    const float4* __restrict__ xs4 = (const float4*)xs;
    for (int r0 = blockIdx.x * 64; r0 < N_NODES; r0 += gridDim.x * 64) {
        const int rows = min(64, N_NODES - r0);
        __syncthreads();
        for (int i = t; i < rows * CH; i += 256) {
            const float xv = xin[(size_t)r0 * CH + i];
            xs[i] = NORM ? fmaf(xv, psc, psh) : xv;
        }
        __syncthreads();
        for (int r = 0; r < rows; ++r) {
            float al = 0.f, ar = 0.f;
#pragma unroll
            for (int k4 = 0; k4 < 8; ++k4) {
                const float4 xv = xs4[r * 8 + k4];      // ds_read_b128 broadcast
                al = fmaf(xv.x, wl[4 * k4 + 0], al);  ar = fmaf(xv.x, wr[4 * k4 + 0], ar);
                al = fmaf(xv.y, wl[4 * k4 + 1], al);  ar = fmaf(xv.y, wr[4 * k4 + 1], ar);
                al = fmaf(xv.z, wl[4 * k4 + 2], al);  ar = fmaf(xv.z, wr[4 * k4 + 2], ar);
                al = fmaf(xv.w, wl[4 * k4 + 3], al);  ar = fmaf(xv.w, wr[4 * k4 + 3], ar);
            }
            xl[(size_t)(r0 + r) * F + t] = f2bf(al);
            xr[(size_t)(r0 + r) * F + t] = f2bf(ar);
        }
    }
}

// ============== single-pass GATv2 aggregation: one wave per dst node ==============
// lane l: head l>>3, channels 4*(l&7)..+3
// unroll-2, two chains, dpp reduce; NEW: gathers software-pipelined one iteration ahead.
#define CHAIN(V, DEN, C0, C1, C2, C3)                                              \
    {                                                                              \
        const float x_ = bf2f(V.x), y_ = bf2f(V.y), z_ = bf2f(V.z), w_ = bf2f(V.w);\
        float s_ = lrelu(x_ + rx, 0.2f) * a4.x                                     \
                 + lrelu(y_ + ry, 0.2f) * a4.y                                     \
                 + lrelu(z_ + rz, 0.2f) * a4.z                                     \
                 + lrelu(w_ + rw, 0.2f) * a4.w;                                    \
        s_ = dpp_sum8(s_);                                                         \
        const float p_ = __expf(s_);                                               \
        DEN += p_;                                                                 \
        C0 = fmaf(p_, x_, C0);                                                     \
        C1 = fmaf(p_, y_, C1);                                                     \
        C2 = fmaf(p_, z_, C2);                                                     \
        C3 = fmaf(p_, w_, C3);                                                     \
    }

__global__ __launch_bounds__(256) void k_agg(
    const int* __restrict__ row_start, const int* __restrict__ row_end,
    const int* __restrict__ csr_src, const unsigned short* __restrict__ xl,
    const unsigned short* __restrict__ xr, const float* __restrict__ att,
    float* __restrict__ accum)
{
    const int lane = threadIdx.x & 63;
    const int wid  = (blockIdx.x * blockDim.x + threadIdx.x) >> 6;
    const int nw   = (gridDim.x * blockDim.x) >> 6;
    const float4 a4 = ((const float4*)att)[lane];
    const ushort4* __restrict__ xl4 = (const ushort4*)xl;
    for (int n = wid; n < N_NODES; n += nw) {
        const ushort4 vru = ((const ushort4*)(xr + (size_t)n * F))[lane];
        const float rx = bf2f(vru.x), ry = bf2f(vru.y), rz = bf2f(vru.z), rw = bf2f(vru.w);
        float c0a = 0.f, c1a = 0.f, c2a = 0.f, c3a = 0.f, dena = 0.f;
        float c0b = 0.f, c1b = 0.f, c2b = 0.f, c3b = 0.f, denb = 0.f;
        const int e0 = row_start[n], e1 = row_end[n];
        const int cnt   = e1 - e0;
        const int pairs = cnt >> 1;
        if (pairs > 0) {
            int e = e0;
            ushort4 va = xl4[(unsigned)csr_src[e]     + (unsigned)lane];
            ushort4 vb = xl4[(unsigned)csr_src[e + 1] + (unsigned)lane];
            e += 2;
            for (int p = 1; p < pairs; ++p, e += 2) {
                // issue NEXT pair's gathers before computing current pair
                const ushort4 vc = xl4[(unsigned)csr_src[e]     + (unsigned)lane];
                const ushort4 vd = xl4[(unsigned)csr_src[e + 1] + (unsigned)lane];
                CHAIN(va, dena, c0a, c1a, c2a, c3a)
                CHAIN(vb, denb, c0b, c1b, c2b, c3b)
                va = vc; vb = vd;
            }
            CHAIN(va, dena, c0a, c1a, c2a, c3a)
            CHAIN(vb, denb, c0b, c1b, c2b, c3b)
        }
        if (cnt & 1) {                             // remainder edge
            const ushort4 va = xl4[(unsigned)csr_src[e1 - 1] + (unsigned)lane];
            CHAIN(va, dena, c0a, c1a, c2a, c3a)
        }
        float c0 = c0a + c0b, c1 = c1a + c1b, c2 = c2a + c2b, c3 = c3a + c3b;
        const float inv = 0.125f / (dena + denb);  // alpha-normalize + head-mean
        c0 *= inv; c1 *= inv; c2 *= inv; c3 *= inv;
#pragma unroll
        for (int off = 8; off <= 32; off <<= 1) {  // sum the 8 heads (per-node, stays on shfl)
            c0 += __shfl_xor(c0, off);
            c1 += __shfl_xor(c1, off);
            c2 += __shfl_xor(c2, off);
            c3 += __shfl_xor(c3, off);
        }
        if (lane < 8)
            ((float4*)(accum + (size_t)n * CH))[lane] = make_float4(c0, c1, c2, c3);
    }
}

// ====== post: y = [lrelu](acc+bias) + residual(bn?(xprev)); batch stats ======
template <int MODE, bool NORM>   // MODE 0: leaky_relu 0.01 + residual, 1: residual only
__global__ __launch_bounds__(256) void k_post(
    float* __restrict__ y, const float* __restrict__ xprev,
    const float* __restrict__ pstats, const float* __restrict__ pg,
    const float* __restrict__ pbe, const float* __restrict__ bias,
    float* __restrict__ stats)
{
    __shared__ float s1[256], s2[256];
    const int t = threadIdx.x;
    const int c = t & 31;
    const float b = bias[c];
    float psc = 1.f, psh = 0.f;
    if (NORM) {
        const float mu  = pstats[c] * (1.f / N_NODES);
        const float var = pstats[32 + c] * (1.f / N_NODES) - mu * mu;
        psc = rsqrtf(var + 1e-5f) * pg[c];
        psh = pbe[c] - mu * psc;
    }
    float ls = 0.f, lq = 0.f;
    for (int i = blockIdx.x * 256 + t; i < N_NODES * CH; i += gridDim.x * 256) {
        float v = y[i] + b;
        if (MODE == 0) v = lrelu(v, 0.01f);
        const float xr_ = xprev[i];
        v += NORM ? fmaf(xr_, psc, psh) : xr_;
        y[i] = v;
        ls += v;
        lq = fmaf(v, v, lq);
    }
    s1[t] = ls; s2[t] = lq;
    __syncthreads();
    if (t < 32) {
        for (int j = 1; j < 8; ++j) { ls += s1[t + 32 * j]; lq += s2[t + 32 * j]; }
        atomicAdd(&stats[c], ls);
        atomicAdd(&stats[32 + c], lq);
    }
}

// ============== final batchnorm normalize → d_out ==============
__global__ __launch_bounds__(256) void k_bn(
    const float* __restrict__ y, const float* __restrict__ stats,
    const float* __restrict__ g, const float* __restrict__ be,
    float* __restrict__ xo)
{
    const int t = threadIdx.x;
    const int c = t & 31;
    const float mu  = stats[c] * (1.f / N_NODES);
    const float var = stats[32 + c] * (1.f / N_NODES) - mu * mu;
    const float sc  = rsqrtf(var + 1e-5f) * g[c];
    const float sh  = be[c] - mu * sc;
    for (int i = blockIdx.x * 256 + t; i < N_NODES * CH; i += gridDim.x * 256)
        xo[i] = fmaf(y[i], sc, sh);
}

extern "C" void kernel_launch(void* const* d_in, const int* in_sizes, int n_in,
                              void* d_out, int out_size, void* d_ws, size_t ws_size,
                              hipStream_t stream)
{
    const float* x0 = (const float*)d_in[0];
    const int*   ei = (const int*)d_in[1];

    char* ws = (char*)d_ws;
    unsigned short* xl    = (unsigned short*)ws;                          // N*256 bf16  51.2 MB
    unsigned short* xr    = xl + (size_t)N_NODES * F;                     // N*256 bf16  51.2 MB
    float*          accA  = (float*)(xr + (size_t)N_NODES * F);           // N*32  f32   12.8 MB
    float*          accB  = accA + (size_t)N_NODES * CH;                  // N*32  f32   12.8 MB
    float*          stats = accB + (size_t)N_NODES * CH;                  // 3*64
    int*            cnt   = (int*)(stats + 192);                          // N (cursor/row_end)
    int*            rowst = cnt + N_NODES;                                // N
    int*            csum  = rowst + N_NODES;                              // NCHUNK
    int*            csr   = csum + NCHUNK;                                // E_TOT  6.8 MB
    const size_t needed = (size_t)((char*)(csr + E_TOT) - ws);            // ~136 MB
    if (ws_size < needed) return;

    const float *Wl[3], *Wr[3], *att[3], *bb[3], *gg[3], *be[3];
    for (int L = 0; L < 3; ++L) {
        Wl[L]  = (const float*)d_in[3 + 6 * L + 0];
        Wr[L]  = (const float*)d_in[3 + 6 * L + 1];
        att[L] = (const float*)d_in[3 + 6 * L + 2];
        bb[L]  = (const float*)d_in[3 + 6 * L + 3];
        gg[L]  = (const float*)d_in[3 + 6 * L + 4];
        be[L]  = (const float*)d_in[3 + 6 * L + 5];
    }
    float* st0 = stats, *st1 = stats + 64, *st2 = stats + 128;

    // ---- CSR build (identical for all 3 layers) ----
    k_deg_init <<<NCHUNK, 256, 0, stream>>>(cnt, stats);
    k_hist     <<<1024,   256, 0, stream>>>(ei, cnt);
    k_scan_chunk<<<NCHUNK, 256, 0, stream>>>(cnt, rowst, csum);
    k_scan_top <<<1,      512, 0, stream>>>(csum);
    k_fill_init<<<NCHUNK, 256, 0, stream>>>(rowst, csum, cnt, csr);
    k_fill     <<<1024,   256, 0, stream>>>(ei, cnt, csr);

    // ---- layer 0: input x0 (raw) ----
    k_gemm<false><<<1563, 256, 0, stream>>>(x0, nullptr, nullptr, nullptr, Wl[0], Wr[0], xl, xr);
    k_agg        <<<2048, 256, 0, stream>>>(rowst, cnt, csr, xl, xr, att[0], accA);
    k_post<0, false><<<1024, 256, 0, stream>>>(accA, x0, nullptr, nullptr, nullptr, bb[0], st0);

    // ---- layer 1: input bn(accA; st0, g0, be0) ----
    k_gemm<true><<<1563, 256, 0, stream>>>(accA, st0, gg[0], be[0], Wl[1], Wr[1], xl, xr);
    k_agg       <<<2048, 256, 0, stream>>>(rowst, cnt, csr, xl, xr, att[1], accB);
    k_post<0, true><<<1024, 256, 0, stream>>>(accB, accA, st0, gg[0], be[0], bb[1], st1);

    // ---- layer 2: input bn(accB; st1, g1, be1) ----
    k_gemm<true><<<1563, 256, 0, stream>>>(accB, st1, gg[1], be[1], Wl[2], Wr[2], xl, xr);
    k_agg       <<<2048, 256, 0, stream>>>(rowst, cnt, csr, xl, xr, att[2], accA);
    k_post<1, true><<<1024, 256, 0, stream>>>(accA, accB, st1, gg[1], be[1], bb[2], st2);

    // ---- final BN -> d_out ----
    k_bn<<<2048, 256, 0, stream>>>(accA, st2, gg[2], be[2], (float*)d_out);

    (void)in_sizes; (void)n_in; (void)out_size;
}

// Round 12
// 907.961 us; speedup vs baseline: 1.2399x; 1.0053x over previous
//
#include <hip/hip_runtime.h>

#define N_NODES 100000
#define N_EDGES 1600000
#define E_TOT   1700000   // edges + self loops
#define HEADS   8
#define CH      32
#define F       256       // HEADS*CH
#define NCHUNK  ((N_NODES + 255) / 256)   // 391
#define EBLK    ((N_EDGES + 255) / 256)   // 6250: one edge per thread

static __device__ __forceinline__ float lrelu(float v, float s) { return fmaxf(v, s * v); }

static __device__ __forceinline__ unsigned short f2bf(float f) {
    unsigned u = __float_as_uint(f);
    u += 0x7FFFu + ((u >> 16) & 1u);      // round-to-nearest-even
    return (unsigned short)(u >> 16);
}
static __device__ __forceinline__ float bf2f(unsigned short u) {
    return __uint_as_float(((unsigned)u) << 16);
}

// 8-lane sum via DPP (VALU-only; validated r6/r10)
static __device__ __forceinline__ float dpp_sum8(float s) {
    s += __uint_as_float(__builtin_amdgcn_mov_dpp(__float_as_uint(s), 0xB1, 0xF, 0xF, true));  // quad_perm [1,0,3,2]
    s += __uint_as_float(__builtin_amdgcn_mov_dpp(__float_as_uint(s), 0x4E, 0xF, 0xF, true));  // quad_perm [2,3,0,1]
    s += __uint_as_float(__builtin_amdgcn_mov_dpp(__float_as_uint(s), 0x141, 0xF, 0xF, true)); // row_half_mirror
    return s;
}

// ======================= CSR build (once per call) =======================
__global__ __launch_bounds__(256) void k_deg_init(int* __restrict__ cnt, float* __restrict__ stats) {
    const int i = blockIdx.x * 256 + threadIdx.x;
    if (i < N_NODES) cnt[i] = 1;          // self loop
    if (blockIdx.x == 0 && threadIdx.x < 192) stats[threadIdx.x] = 0.f;
}

// one edge per thread: max wave-parallelism for latency-bound atomics
__global__ __launch_bounds__(256) void k_hist(const int* __restrict__ ei, int* __restrict__ cnt) {
    const int e = blockIdx.x * 256 + threadIdx.x;
    if (e < N_EDGES) atomicAdd(&cnt[ei[N_EDGES + e]], 1);
}

__global__ __launch_bounds__(256) void k_scan_chunk(
    const int* __restrict__ cnt, int* __restrict__ row_start, int* __restrict__ csum)
{
    __shared__ int s[256];
    const int t = threadIdx.x;
    const int i = blockIdx.x * 256 + t;
    const int v = (i < N_NODES) ? cnt[i] : 0;
    s[t] = v;
    __syncthreads();
    for (int off = 1; off < 256; off <<= 1) {
        const int y = (t >= off) ? s[t - off] : 0;
        __syncthreads();
        s[t] += y;
        __syncthreads();
    }
    if (i < N_NODES) row_start[i] = s[t] - v;   // exclusive
    if (t == 255) csum[blockIdx.x] = s[t];
}

__global__ __launch_bounds__(512) void k_scan_top(int* __restrict__ csum) {
    __shared__ int s[512];
    const int t = threadIdx.x;
    const int v = (t < NCHUNK) ? csum[t] : 0;
    s[t] = v;
    __syncthreads();
    for (int off = 1; off < 512; off <<= 1) {
        const int y = (t >= off) ? s[t - off] : 0;
        __syncthreads();
        s[t] += y;
        __syncthreads();
    }
    if (t < NCHUNK) csum[t] = s[t] - v;         // exclusive
}

__global__ __launch_bounds__(256) void k_fill_init(
    int* __restrict__ row_start, const int* __restrict__ csum,
    int* __restrict__ cursor, int* __restrict__ csr_src)
{
    const int i = blockIdx.x * 256 + threadIdx.x;
    if (i >= N_NODES) return;
    const int rs = row_start[i] + csum[i >> 8];
    row_start[i] = rs;
    cursor[i] = rs + 1;
    csr_src[rs] = i * 64;                       // self loop first (pre-scaled: ushort4-element offset)
}

// one edge per thread
__global__ __launch_bounds__(256) void k_fill(
    const int* __restrict__ ei, int* __restrict__ cursor, int* __restrict__ csr_src)
{
    const int e = blockIdx.x * 256 + threadIdx.x;
    if (e < N_EDGES) {
        const int pos = atomicAdd(&cursor[ei[N_EDGES + e]], 1);
        csr_src[pos] = ei[e] * 64;              // pre-scaled
    }
}
// after k_fill: cursor[i] == row_end[i]

// ====== xl = bn?(x) @ Wl (bf16), xr = bn?(x) @ Wr (bf16)  ([N,32]@[32,256]) ======
template <bool NORM>
__global__ __launch_bounds__(256) void k_gemm(
    const float* __restrict__ xin, const float* __restrict__ pstats,
    const float* __restrict__ pg, const float* __restrict__ pbe,
    const float* __restrict__ Wl, const float* __restrict__ Wr,
    unsigned short* __restrict__ xl, unsigned short* __restrict__ xr)
{
    __shared__ float xs[64 * CH];
    const int t = threadIdx.x;
    const int c = t & 31;
    float psc = 1.f, psh = 0.f;
    if (NORM) {
        const float mu  = pstats[c] * (1.f / N_NODES);
        const float var = pstats[32 + c] * (1.f / N_NODES) - mu * mu;
        psc = rsqrtf(var + 1e-5f) * pg[c];
        psh = pbe[c] - mu * psc;
    }
    float wl[CH], wr[CH];
#pragma unroll
    for (int k = 0; k < CH; ++k) {
        wl[k] = Wl[k * F + t];
        wr[k] = Wr[k * F + t];
    }
    const float4* __restrict__ xs4 = (const float4*)xs;
    for (int r0 = blockIdx.x * 64; r0 < N_NODES; r0 += gridDim.x * 64) {
        const int rows = min(64, N_NODES - r0);
        __syncthreads();
        for (int i = t; i < rows * CH; i += 256) {
            const float xv = xin[(size_t)r0 * CH + i];
            xs[i] = NORM ? fmaf(xv, psc, psh) : xv;
        }
        __syncthreads();
        for (int r = 0; r < rows; ++r) {
            float al = 0.f, ar = 0.f;
#pragma unroll
            for (int k4 = 0; k4 < 8; ++k4) {
                const float4 xv = xs4[r * 8 + k4];      // ds_read_b128 broadcast
                al = fmaf(xv.x, wl[4 * k4 + 0], al);  ar = fmaf(xv.x, wr[4 * k4 + 0], ar);
                al = fmaf(xv.y, wl[4 * k4 + 1], al);  ar = fmaf(xv.y, wr[4 * k4 + 1], ar);
                al = fmaf(xv.z, wl[4 * k4 + 2], al);  ar = fmaf(xv.z, wr[4 * k4 + 2], ar);
                al = fmaf(xv.w, wl[4 * k4 + 3], al);  ar = fmaf(xv.w, wr[4 * k4 + 3], ar);
            }
            xl[(size_t)(r0 + r) * F + t] = f2bf(al);
            xr[(size_t)(r0 + r) * F + t] = f2bf(ar);
        }
    }
}

// ============== single-pass GATv2 aggregation: one wave per dst node ==============
// lane l: head l>>3, channels 4*(l&7)..+3
// unroll-2, two chains, dpp reduce, gathers software-pipelined one iteration ahead (r11).
#define CHAIN(V, DEN, C0, C1, C2, C3)                                              \
    {                                                                              \
        const float x_ = bf2f(V.x), y_ = bf2f(V.y), z_ = bf2f(V.z), w_ = bf2f(V.w);\
        float s_ = lrelu(x_ + rx, 0.2f) * a4.x                                     \
                 + lrelu(y_ + ry, 0.2f) * a4.y                                     \
                 + lrelu(z_ + rz, 0.2f) * a4.z                                     \
                 + lrelu(w_ + rw, 0.2f) * a4.w;                                    \
        s_ = dpp_sum8(s_);                                                         \
        const float p_ = __expf(s_);                                               \
        DEN += p_;                                                                 \
        C0 = fmaf(p_, x_, C0);                                                     \
        C1 = fmaf(p_, y_, C1);                                                     \
        C2 = fmaf(p_, z_, C2);                                                     \
        C3 = fmaf(p_, w_, C3);                                                     \
    }

__global__ __launch_bounds__(256) void k_agg(
    const int* __restrict__ row_start, const int* __restrict__ row_end,
    const int* __restrict__ csr_src, const unsigned short* __restrict__ xl,
    const unsigned short* __restrict__ xr, const float* __restrict__ att,
    float* __restrict__ accum)
{
    const int lane = threadIdx.x & 63;
    const int wid  = (blockIdx.x * blockDim.x + threadIdx.x) >> 6;
    const int nw   = (gridDim.x * blockDim.x) >> 6;
    const float4 a4 = ((const float4*)att)[lane];
    const ushort4* __restrict__ xl4 = (const ushort4*)xl;
    for (int n = wid; n < N_NODES; n += nw) {
        const ushort4 vru = ((const ushort4*)(xr + (size_t)n * F))[lane];
        const float rx = bf2f(vru.x), ry = bf2f(vru.y), rz = bf2f(vru.z), rw = bf2f(vru.w);
        float c0a = 0.f, c1a = 0.f, c2a = 0.f, c3a = 0.f, dena = 0.f;
        float c0b = 0.f, c1b = 0.f, c2b = 0.f, c3b = 0.f, denb = 0.f;
        const int e0 = row_start[n], e1 = row_end[n];
        const int cnt   = e1 - e0;
        const int pairs = cnt >> 1;
        if (pairs > 0) {
            int e = e0;
            ushort4 va = xl4[(unsigned)csr_src[e]     + (unsigned)lane];
            ushort4 vb = xl4[(unsigned)csr_src[e + 1] + (unsigned)lane];
            e += 2;
            for (int p = 1; p < pairs; ++p, e += 2) {
                // issue NEXT pair's gathers before computing current pair
                const ushort4 vc = xl4[(unsigned)csr_src[e]     + (unsigned)lane];
                const ushort4 vd = xl4[(unsigned)csr_src[e + 1] + (unsigned)lane];
                CHAIN(va, dena, c0a, c1a, c2a, c3a)
                CHAIN(vb, denb, c0b, c1b, c2b, c3b)
                va = vc; vb = vd;
            }
            CHAIN(va, dena, c0a, c1a, c2a, c3a)
            CHAIN(vb, denb, c0b, c1b, c2b, c3b)
        }
        if (cnt & 1) {                             // remainder edge
            const ushort4 va = xl4[(unsigned)csr_src[e1 - 1] + (unsigned)lane];
            CHAIN(va, dena, c0a, c1a, c2a, c3a)
        }
        float c0 = c0a + c0b, c1 = c1a + c1b, c2 = c2a + c2b, c3 = c3a + c3b;
        const float inv = 0.125f / (dena + denb);  // alpha-normalize + head-mean
        c0 *= inv; c1 *= inv; c2 *= inv; c3 *= inv;
#pragma unroll
        for (int off = 8; off <= 32; off <<= 1) {  // sum the 8 heads
            c0 += __shfl_xor(c0, off);
            c1 += __shfl_xor(c1, off);
            c2 += __shfl_xor(c2, off);
            c3 += __shfl_xor(c3, off);
        }
        if (lane < 8)
            ((float4*)(accum + (size_t)n * CH))[lane] = make_float4(c0, c1, c2, c3);
    }
}

// ====== post: y = [lrelu](acc+bias) + residual(bn?(xprev)); batch stats ======
template <int MODE, bool NORM>   // MODE 0: leaky_relu 0.01 + residual, 1: residual only
__global__ __launch_bounds__(256) void k_post(
    float* __restrict__ y, const float* __restrict__ xprev,
    const float* __restrict__ pstats, const float* __restrict__ pg,
    const float* __restrict__ pbe, const float* __restrict__ bias,
    float* __restrict__ stats)
{
    __shared__ float s1[256], s2[256];
    const int t = threadIdx.x;
    const int c = t & 31;
    const float b = bias[c];
    float psc = 1.f, psh = 0.f;
    if (NORM) {
        const float mu  = pstats[c] * (1.f / N_NODES);
        const float var = pstats[32 + c] * (1.f / N_NODES) - mu * mu;
        psc = rsqrtf(var + 1e-5f) * pg[c];
        psh = pbe[c] - mu * psc;
    }
    float ls = 0.f, lq = 0.f;
    for (int i = blockIdx.x * 256 + t; i < N_NODES * CH; i += gridDim.x * 256) {
        float v = y[i] + b;
        if (MODE == 0) v = lrelu(v, 0.01f);
        const float xr_ = xprev[i];
        v += NORM ? fmaf(xr_, psc, psh) : xr_;
        y[i] = v;
        ls += v;
        lq = fmaf(v, v, lq);
    }
    s1[t] = ls; s2[t] = lq;
    __syncthreads();
    if (t < 32) {
        for (int j = 1; j < 8; ++j) { ls += s1[t + 32 * j]; lq += s2[t + 32 * j]; }
        atomicAdd(&stats[c], ls);
        atomicAdd(&stats[32 + c], lq);
    }
}

// ============== final batchnorm normalize → d_out ==============
__global__ __launch_bounds__(256) void k_bn(
    const float* __restrict__ y, const float* __restrict__ stats,
    const float* __restrict__ g, const float* __restrict__ be,
    float* __restrict__ xo)
{
    const int t = threadIdx.x;
    const int c = t & 31;
    const float mu  = stats[c] * (1.f / N_NODES);
    const float var = stats[32 + c] * (1.f / N_NODES) - mu * mu;
    const float sc  = rsqrtf(var + 1e-5f) * g[c];
    const float sh  = be[c] - mu * sc;
    for (int i = blockIdx.x * 256 + t; i < N_NODES * CH; i += gridDim.x * 256)
        xo[i] = fmaf(y[i], sc, sh);
}

extern "C" void kernel_launch(void* const* d_in, const int* in_sizes, int n_in,
                              void* d_out, int out_size, void* d_ws, size_t ws_size,
                              hipStream_t stream)
{
    const float* x0 = (const float*)d_in[0];
    const int*   ei = (const int*)d_in[1];

    char* ws = (char*)d_ws;
    unsigned short* xl    = (unsigned short*)ws;                          // N*256 bf16  51.2 MB
    unsigned short* xr    = xl + (size_t)N_NODES * F;                     // N*256 bf16  51.2 MB
    float*          accA  = (float*)(xr + (size_t)N_NODES * F);           // N*32  f32   12.8 MB
    float*          accB  = accA + (size_t)N_NODES * CH;                  // N*32  f32   12.8 MB
    float*          stats = accB + (size_t)N_NODES * CH;                  // 3*64
    int*            cnt   = (int*)(stats + 192);                          // N (cursor/row_end)
    int*            rowst = cnt + N_NODES;                                // N
    int*            csum  = rowst + N_NODES;                              // NCHUNK
    int*            csr   = csum + NCHUNK;                                // E_TOT  6.8 MB
    const size_t needed = (size_t)((char*)(csr + E_TOT) - ws);            // ~136 MB
    if (ws_size < needed) return;

    const float *Wl[3], *Wr[3], *att[3], *bb[3], *gg[3], *be[3];
    for (int L = 0; L < 3; ++L) {
        Wl[L]  = (const float*)d_in[3 + 6 * L + 0];
        Wr[L]  = (const float*)d_in[3 + 6 * L + 1];
        att[L] = (const float*)d_in[3 + 6 * L + 2];
        bb[L]  = (const float*)d_in[3 + 6 * L + 3];
        gg[L]  = (const float*)d_in[3 + 6 * L + 4];
        be[L]  = (const float*)d_in[3 + 6 * L + 5];
    }
    float* st0 = stats, *st1 = stats + 64, *st2 = stats + 128;

    // ---- CSR build (identical for all 3 layers) ----
    k_deg_init <<<NCHUNK, 256, 0, stream>>>(cnt, stats);
    k_hist     <<<EBLK,   256, 0, stream>>>(ei, cnt);
    k_scan_chunk<<<NCHUNK, 256, 0, stream>>>(cnt, rowst, csum);
    k_scan_top <<<1,      512, 0, stream>>>(csum);
    k_fill_init<<<NCHUNK, 256, 0, stream>>>(rowst, csum, cnt, csr);
    k_fill     <<<EBLK,   256, 0, stream>>>(ei, cnt, csr);

    // ---- layer 0: input x0 (raw) ----
    k_gemm<false><<<1563, 256, 0, stream>>>(x0, nullptr, nullptr, nullptr, Wl[0], Wr[0], xl, xr);
    k_agg        <<<2048, 256, 0, stream>>>(rowst, cnt, csr, xl, xr, att[0], accA);
    k_post<0, false><<<1024, 256, 0, stream>>>(accA, x0, nullptr, nullptr, nullptr, bb[0], st0);

    // ---- layer 1: input bn(accA; st0, g0, be0) ----
    k_gemm<true><<<1563, 256, 0, stream>>>(accA, st0, gg[0], be[0], Wl[1], Wr[1], xl, xr);
    k_agg       <<<2048, 256, 0, stream>>>(rowst, cnt, csr, xl, xr, att[1], accB);
    k_post<0, true><<<1024, 256, 0, stream>>>(accB, accA, st0, gg[0], be[0], bb[1], st1);

    // ---- layer 2: input bn(accB; st1, g1, be1) ----
    k_gemm<true><<<1563, 256, 0, stream>>>(accB, st1, gg[1], be[1], Wl[2], Wr[2], xl, xr);
    k_agg       <<<2048, 256, 0, stream>>>(rowst, cnt, csr, xl, xr, att[2], accA);
    k_post<1, true><<<1024, 256, 0, stream>>>(accA, accB, st1, gg[1], be[1], bb[2], st2);

    // ---- final BN -> d_out ----
    k_bn<<<2048, 256, 0, stream>>>(accA, st2, gg[2], be[2], (float*)d_out);

    (void)in_sizes; (void)n_in; (void)out_size;
}